// Round 1
// 1687.519 us; speedup vs baseline: 1.6113x; 1.6113x over previous
//
#include <hip/hip_runtime.h>
#include <math.h>

#define N_NODE 200
#define RING   512
#define NSTEP  500
#define TB     16
#define NB     32          // ceil(500/16)
#define NWG    8
#define NTHR   256
#define JSL    25          // j-rows per WG slice
#define NEARCAP 24

// ---- ws layout (float element offsets) ----
#define OFF_FP   0         // [NWG][200][TB] far partial sums (plain float4, fenced by barrier)
#define OFF_BAR  25600     // [64] int barrier counters
#define WS_NEED  ((size_t)(25600 + 64) * 4)

// ---- static LDS layout (byte offsets into smem[]) ----
#define SM_RED   0         // double[6]
#define SM_MREC  64        // float[32*200]   recent M history
#define SM_NJD   25664     // u32 [200*24]    near (j | d<<16)
#define SM_NW    44864     // float[200*24]   near weights
#define SM_NCNT  64064     // int[200]
#define SM_LED   64864     // float[16*200]   far sums for block
#define SM_US    77664     // float[16*200]   u prefetch
#define SM_NS    90464     // float[16*200]   noise prefetch
#define SM_RING  103264    // float[25*512]   own j-slice M ring (LDS-resident!)
#define SM_LMT   64        // float[64*200]   (WG0 epilogue overlay)
#define SM_DIFF  51264     // float[200*50]   (WG0 epilogue overlay)
#define SM_TOTAL 154464

__device__ __forceinline__ float sigm(float x) {
    return 5.0f / (1.0f + expf(0.56f * (6.0f - x)));
}
__device__ __forceinline__ float satf(float x) {
    return 1000.0f * tanhf(x / 1000.0f);
}

__device__ __forceinline__ void grid_barrier(int* slot, int nwg) {
    __syncthreads();
    if (threadIdx.x == 0) {
        __threadfence();
        __hip_atomic_fetch_add(slot, 1, __ATOMIC_ACQ_REL, __HIP_MEMORY_SCOPE_AGENT);
        while (__hip_atomic_load(slot, __ATOMIC_ACQUIRE, __HIP_MEMORY_SCOPE_AGENT) < nwg) {
            __builtin_amdgcn_s_sleep(2);
        }
        __threadfence();
    }
    __syncthreads();
}

__global__ void zero_bar(int* bar) {
    if (threadIdx.x < 64) bar[threadIdx.x] = 0;
}

__global__ __launch_bounds__(NTHR, 1)
void jansen_mw(const float* __restrict__ inp, const float* __restrict__ noise_in,
               const float* __restrict__ hx,  const float* __restrict__ hE,
               const float* __restrict__ sc,  const float* __restrict__ wbb,
               const float* __restrict__ lm,  const int*   __restrict__ delays,
               float* __restrict__ out, float* __restrict__ ws)
{
    __shared__ char smem[SM_TOTAL];
    double*   red  = (double*)(smem + SM_RED);
    float*    Mrec = (float*)(smem + SM_MREC);
    unsigned* nJD  = (unsigned*)(smem + SM_NJD);
    float*    nW   = (float*)(smem + SM_NW);
    int*      nCnt = (int*)(smem + SM_NCNT);
    float*    LEdS = (float*)(smem + SM_LED);
    float*    uS   = (float*)(smem + SM_US);
    float*    nS   = (float*)(smem + SM_NS);
    float*    ringS= (float*)(smem + SM_RING);

    const int tid = threadIdx.x;
    const int wg  = blockIdx.x;
    const int i   = tid;            // node id (active if < 200)
    const int jlo = wg * JSL;

    float* fp    = ws + OFF_FP;
    int*   bar   = (int*)(ws + OFF_BAR);

    // ---- pass A: Frobenius norm of wl (redundant per WG) ----
    double ssq = 0.0;
    for (int q = tid; q < N_NODE * N_NODE; q += NTHR) {
        int j = q / N_NODE, ii = q - j * N_NODE;
        float w1 = expf(wbb[ii * N_NODE + j]) * sc[ii * N_NODE + j];
        float w2 = expf(wbb[j * N_NODE + ii]) * sc[j * N_NODE + ii];
        float wl = log1pf(0.5f * (w1 + w2));
        ssq += (double)wl * (double)wl;
    }
    #pragma unroll
    for (int off = 32; off > 0; off >>= 1) ssq += __shfl_down(ssq, off, 64);
    if ((tid & 63) == 0) red[tid >> 6] = ssq;

    // ---- ring init (own slice, single copy, LDS) ----
    for (int p = tid; p < JSL * RING; p += NTHR) {
        int jl = p >> 9, x = p & 511;
        int dd = 511 - x;
        ringS[p] = (dd < 500) ? hE[(jlo + jl) * 500 + dd] : 0.0f;
    }
    // ---- Mrec init: slot s for s in [-32,-1], dd = 31-slot ----
    for (int p = tid; p < 32 * N_NODE; p += NTHR) {
        int slot = p / N_NODE, j = p - slot * N_NODE;
        Mrec[p] = hE[j * 500 + (31 - slot)];
    }
    __syncthreads();
    if (tid == 0) {
        double s = red[0] + red[1] + red[2] + red[3];
        red[4] = 1.0 / sqrt(s);
    }
    __syncthreads();
    const float inv = (float)red[4];

    // ---- pass B: near lists, rowsum, state; own-slice weights into REGISTERS ----
    float rowsum = 0.0f;
    float M = 0, E = 0, I = 0, Mvv = 0, Evv = 0, Ivv = 0;
    float wreg[JSL];
    int   ereg[JSL];
    #pragma unroll
    for (int jl = 0; jl < JSL; ++jl) { wreg[jl] = 0.0f; ereg[jl] = 0; }
    if (i < N_NODE) {
        int cnt = 0;
        for (int j = 0; j < N_NODE; ++j) {
            float w1 = expf(wbb[i * N_NODE + j]) * sc[i * N_NODE + j];
            float w2 = expf(wbb[j * N_NODE + i]) * sc[j * N_NODE + i];
            float w  = log1pf(0.5f * (w1 + w2)) * inv;
            int d = delays[j * N_NODE + i];
            rowsum += w;
            if (d < TB) {
                if (cnt < NEARCAP) {
                    nJD[i * NEARCAP + cnt] = (unsigned)(j | (d << 16));
                    nW [i * NEARCAP + cnt] = w;
                }
                ++cnt;
            }
        }
        nCnt[i] = (cnt < NEARCAP) ? cnt : NEARCAP;
        // own-slice far weights -> registers (recompute 25 of the above)
        #pragma unroll
        for (int jl = 0; jl < JSL; ++jl) {
            int j = jlo + jl;
            float w1 = expf(wbb[i * N_NODE + j]) * sc[i * N_NODE + j];
            float w2 = expf(wbb[j * N_NODE + i]) * sc[j * N_NODE + i];
            float w  = log1pf(0.5f * (w1 + w2)) * inv;
            int d = delays[j * N_NODE + i];
            wreg[jl] = (d < TB) ? 0.0f : w;
            ereg[jl] = 511 - d;
        }
        M   = hx[i * 6 + 0]; E   = hx[i * 6 + 1]; I   = hx[i * 6 + 2];
        Mvv = hx[i * 6 + 3]; Evv = hx[i * 6 + 4]; Ivv = hx[i * 6 + 5];
    }
    __syncthreads();

    // ---------------- main loop over 16-step blocks ----------------
    for (int b = 0; b < NB; ++b) {
        const int t0 = b * TB;

        // ---- far phase: own j-slice from LDS ring, weights in registers ----
        if (i < N_NODE) {
            float ac[16];
            #pragma unroll
            for (int k = 0; k < 16; ++k) ac[k] = 0.0f;
            #pragma unroll
            for (int jl = 0; jl < JSL; ++jl) {
                float w  = wreg[jl];
                int   p0 = (t0 + ereg[jl]) & 511;
                const float* rb = ringS + (jl << 9);
                #pragma unroll
                for (int k = 0; k < 16; ++k)
                    ac[k] = fmaf(w, rb[(p0 + k) & 511], ac[k]);
            }
            float4* fpw = (float4*)(fp + wg * (TB * N_NODE) + i * TB);
            fpw[0] = make_float4(ac[ 0], ac[ 1], ac[ 2], ac[ 3]);
            fpw[1] = make_float4(ac[ 4], ac[ 5], ac[ 6], ac[ 7]);
            fpw[2] = make_float4(ac[ 8], ac[ 9], ac[10], ac[11]);
            fpw[3] = make_float4(ac[12], ac[13], ac[14], ac[15]);

            // prefetch u/noise before the barrier (latency hides under spin)
            #pragma unroll
            for (int k = 0; k < TB; ++k) {
                int t = t0 + k;
                if (t < NSTEP) {
                    int bb = t / 10, h = t - 10 * bb;
                    uS[k * N_NODE + i] = inp     [i * 500 + h * 50 + bb];
                    nS[k * N_NODE + i] = noise_in[i * 500 + h * 50 + bb];
                }
            }
        }

        grid_barrier(bar + b, NWG);

        // ---- gather partials: 8 x 4 float4 loads, full MLP ----
        if (i < N_NODE) {
            float s0=0,s1=0,s2=0,s3=0,s4=0,s5=0,s6=0,s7=0;
            float s8=0,s9=0,s10=0,s11=0,s12=0,s13=0,s14=0,s15=0;
            #pragma unroll
            for (int g2 = 0; g2 < NWG; ++g2) {
                const float4* q = (const float4*)(fp + g2 * (TB * N_NODE) + i * TB);
                float4 a0 = q[0], a1 = q[1], a2 = q[2], a3 = q[3];
                s0  += a0.x; s1  += a0.y; s2  += a0.z; s3  += a0.w;
                s4  += a1.x; s5  += a1.y; s6  += a1.z; s7  += a1.w;
                s8  += a2.x; s9  += a2.y; s10 += a2.z; s11 += a2.w;
                s12 += a3.x; s13 += a3.y; s14 += a3.z; s15 += a3.w;
            }
            LEdS[ 0 * N_NODE + i] = s0;  LEdS[ 1 * N_NODE + i] = s1;
            LEdS[ 2 * N_NODE + i] = s2;  LEdS[ 3 * N_NODE + i] = s3;
            LEdS[ 4 * N_NODE + i] = s4;  LEdS[ 5 * N_NODE + i] = s5;
            LEdS[ 6 * N_NODE + i] = s6;  LEdS[ 7 * N_NODE + i] = s7;
            LEdS[ 8 * N_NODE + i] = s8;  LEdS[ 9 * N_NODE + i] = s9;
            LEdS[10 * N_NODE + i] = s10; LEdS[11 * N_NODE + i] = s11;
            LEdS[12 * N_NODE + i] = s12; LEdS[13 * N_NODE + i] = s13;
            LEdS[14 * N_NODE + i] = s14; LEdS[15 * N_NODE + i] = s15;
        }
        __syncthreads();

        // ---- inner per-step phase (redundant in every WG) ----
        int kmax = (NSTEP - t0 < TB) ? (NSTEP - t0) : TB;
        for (int k = 0; k < kmax; ++k) {
            int t = t0 + k;
            if (i < N_NODE) {
                float LEd = LEdS[k * N_NODE + i];
                int cnt = nCnt[i];
                for (int n = 0; n < cnt; ++n) {
                    unsigned jd = nJD[i * NEARCAP + n];
                    int j = jd & 0xffff, d = (int)(jd >> 16);
                    LEd = fmaf(nW[i * NEARCAP + n], Mrec[((t - 1 - d) & 31) * N_NODE + j], LEd);
                }
                float u  = uS[k * N_NODE + i];
                float nz = nS[k * N_NODE + i];
                float rM = sigm(E - I);
                float rE = 250.0f * nz + 1000.01f * (LEd - rowsum * E) + 108.01f * sigm(135.01f * M);
                float rI = 33.76f * sigm(33.76f * M);
                float ddM = M + 1e-4f * Mvv;
                float ddE = E + 1e-4f * Evv;
                float ddI = I + 1e-4f * Ivv;
                float uu  = u + 500.0f * tanhf(rM / 500.0f);
                float ddMv = Mvv + 1e-4f * (328.25f * uu - 202.0f * Mvv - 10201.0f * M);
                float uE  = 500.0f * tanhf(rE / 500.0f);
                float ddEv = Evv + 1e-4f * (328.25f * uE - 202.0f * Evv - 10201.0f * E);
                float uI  = 500.0f * tanhf(rI / 500.0f);
                float ddIv = Ivv + 1e-4f * (1122.0f * uI - 102.0f * Ivv - 2601.0f * I);
                M   = satf(ddM);  E   = satf(ddE);  I   = satf(ddI);
                Mvv = satf(ddMv); Evv = satf(ddEv); Ivv = satf(ddIv);
                Mrec[(t & 31) * N_NODE + i] = M;
                if (i >= jlo && i < jlo + JSL) {
                    ringS[((i - jlo) << 9) | (t & 511)] = M;
                }
                if (wg == 0) {
                    int bb = t / 10, h = t - 10 * bb;
                    if (h == 9) {
                        out[ 4400 + i * 50 + bb] = E;
                        out[14400 + i * 50 + bb] = I;
                        out[24400 + i * 50 + bb] = M;
                        out[34400 + i * 50 + bb] = Evv;
                        out[44400 + i * 50 + bb] = Ivv;
                        out[54400 + i * 50 + bb] = Mvv;
                    }
                }
            }
            __syncthreads();
        }
    }

    // ---------------- epilogue ----------------
    // hEb slice: rows [jlo, jlo+JSL) from LDS ring
    for (int p = tid; p < JSL * 500; p += NTHR) {
        int jl = p / 500, dd = p - jl * 500;
        out[64400 + (jlo + jl) * 500 + dd] = ringS[(jl << 9) + ((499 - dd) & 511)];
    }
    if (wg != 0) return;

    if (i < N_NODE) {
        out[3200 + i * 6 + 0] = M;
        out[3200 + i * 6 + 1] = E;
        out[3200 + i * 6 + 2] = I;
        out[3200 + i * 6 + 3] = Mvv;
        out[3200 + i * 6 + 4] = Evv;
        out[3200 + i * 6 + 5] = Ivv;
    }

    float* lmt  = (float*)(smem + SM_LMT);
    float* diff = (float*)(smem + SM_DIFF);
    __syncthreads();
    if (tid < 64) {
        float s = 0.0f;
        for (int n = 0; n < N_NODE; ++n) { float v = lm[tid * N_NODE + n]; s += v * v; }
        float ivn = 1.0f / sqrtf(s);
        for (int n = 0; n < N_NODE; ++n) lmt[tid * N_NODE + n] = lm[tid * N_NODE + n] * ivn;
    }
    __syncthreads();
    if (tid < N_NODE) {
        float s = 0.0f;
        for (int o = 0; o < 64; ++o) s += lmt[o * N_NODE + tid];
        s *= (1.0f / 64.0f);
        for (int o = 0; o < 64; ++o) lmt[o * N_NODE + tid] -= s;
    }
    __syncthreads();
    for (int p = tid; p < 10000; p += NTHR) diff[p] = out[4400 + p] - out[14400 + p];
    __syncthreads();
    for (int p = tid; p < 3200; p += NTHR) {
        int o = p / 50, bb = p - o * 50;
        float s = 0.0f;
        for (int n = 0; n < N_NODE; ++n)
            s = fmaf(lmt[o * N_NODE + n], diff[n * 50 + bb], s);
        out[p] = 5.0f * s - 2.0f;
    }
}

// ---------------- fallback: round-1 single-WG kernel ----------------
__global__ __launch_bounds__(1024, 1)
void jansen_main(const float* __restrict__ inp, const float* __restrict__ noise_in,
                 const float* __restrict__ hx,  const float* __restrict__ hE,
                 const float* __restrict__ sc,  const float* __restrict__ wbb,
                 const float* __restrict__ lm,  const int*   __restrict__ delays,
                 float* __restrict__ out, float* __restrict__ ws)
{
    const int tid = threadIdx.x;
    const int i   = tid & 255;
    const int c   = tid >> 8;

    float* ring = ws;
    float* lmt  = ws + N_NODE * RING;

    __shared__ double red[18];
    __shared__ float  part[4][N_NODE];
    __shared__ float  wn[N_NODE * N_NODE];

    double ssq = 0.0;
    for (int p = tid; p < N_NODE * N_NODE; p += 1024) {
        int r0 = p / N_NODE;
        int cc = p - r0 * N_NODE;
        float w1 = expf(wbb[p]) * sc[p];
        float w2 = expf(wbb[cc * N_NODE + r0]) * sc[cc * N_NODE + r0];
        float v  = log1pf(0.5f * (w1 + w2));
        wn[p] = v;
        ssq += (double)v * (double)v;
    }
    #pragma unroll
    for (int off = 32; off > 0; off >>= 1) ssq += __shfl_down(ssq, off, 64);
    if ((tid & 63) == 0) red[tid >> 6] = ssq;
    __syncthreads();
    if (tid == 0) {
        double s = 0.0;
        for (int k = 0; k < 16; ++k) s += red[k];
        red[16] = 1.0 / sqrt(s);
    }
    __syncthreads();
    const float inv_norm = (float)red[16];
    for (int p = tid; p < N_NODE * N_NODE; p += 1024) wn[p] *= inv_norm;

    for (int p = tid; p < N_NODE * 500; p += 1024) {
        int j = p / 500, dd = p - j * 500;
        ring[j * RING + (511 - dd)] = hE[p];
    }
    if (tid < 64) {
        float s = 0.0f;
        for (int n = 0; n < N_NODE; ++n) { float v = lm[tid * N_NODE + n]; s += v * v; }
        float inv = 1.0f / sqrtf(s);
        for (int n = 0; n < N_NODE; ++n) lmt[tid * N_NODE + n] = lm[tid * N_NODE + n] * inv;
    }
    __syncthreads();
    if (tid < N_NODE) {
        float s = 0.0f;
        for (int o = 0; o < 64; ++o) s += lmt[o * N_NODE + tid];
        s *= (1.0f / 64.0f);
        for (int o = 0; o < 64; ++o) lmt[o * N_NODE + tid] -= s;
    }

    unsigned int dpk[25];
    if (i < N_NODE) {
        #pragma unroll
        for (int r0 = 0; r0 < 25; ++r0) {
            int d0 = delays[(c * 50 + 2 * r0    ) * N_NODE + i];
            int d1 = delays[(c * 50 + 2 * r0 + 1) * N_NODE + i];
            unsigned e0 = (unsigned)((-1 - d0) & 511);
            unsigned e1 = (unsigned)((-1 - d1) & 511);
            dpk[r0] = e0 | (e1 << 16);
        }
    }

    float M = 0, E = 0, I = 0, Mvv = 0, Evv = 0, Ivv = 0, rowsum = 0;
    if (c == 0 && i < N_NODE) {
        M   = hx[i * 6 + 0]; E   = hx[i * 6 + 1]; I   = hx[i * 6 + 2];
        Mvv = hx[i * 6 + 3]; Evv = hx[i * 6 + 4]; Ivv = hx[i * 6 + 5];
    }
    __syncthreads();
    if (c == 0 && i < N_NODE) {
        float s = 0.0f;
        for (int j = 0; j < N_NODE; ++j) s += wn[j * N_NODE + i];
        rowsum = s;
    }

    for (int t = 0; t < NSTEP; ++t) {
        if (i < N_NODE) {
            float acc = 0.0f;
            const float* ringc = ring + c * 50 * RING;
            const float* wnc   = wn + c * 50 * N_NODE + i;
            #pragma unroll
            for (int r0 = 0; r0 < 50; ++r0) {
                unsigned e = (dpk[r0 >> 1] >> ((r0 & 1) << 4)) & 0xffffu;
                int pos = (int)(((unsigned)t + e) & 511u);
                acc = fmaf(wnc[r0 * N_NODE], ringc[r0 * RING + pos], acc);
            }
            part[c][i] = acc;
        }
        __syncthreads();
        if (c == 0 && i < N_NODE) {
            float LEd = part[0][i] + part[1][i] + part[2][i] + part[3][i];
            int b = t / 10, h = t - b * 10;
            float u  = inp     [i * 500 + h * 50 + b];
            float nz = noise_in[i * 500 + h * 50 + b];
            float rM = sigm(E - I);
            float rE = 250.0f * nz + 1000.01f * (LEd - rowsum * E) + 108.01f * sigm(135.01f * M);
            float rI = 33.76f * sigm(33.76f * M);
            float ddM = M + 1e-4f * Mvv;
            float ddE = E + 1e-4f * Evv;
            float ddI = I + 1e-4f * Ivv;
            float uu  = u + 500.0f * tanhf(rM / 500.0f);
            float ddMv = Mvv + 1e-4f * (328.25f * uu - 202.0f * Mvv - 10201.0f * M);
            float uE  = 500.0f * tanhf(rE / 500.0f);
            float ddEv = Evv + 1e-4f * (328.25f * uE - 202.0f * Evv - 10201.0f * E);
            float uI  = 500.0f * tanhf(rI / 500.0f);
            float ddIv = Ivv + 1e-4f * (1122.0f * uI - 102.0f * Ivv - 2601.0f * I);
            M   = satf(ddM);  E   = satf(ddE);  I   = satf(ddI);
            Mvv = satf(ddMv); Evv = satf(ddEv); Ivv = satf(ddIv);
            ring[i * RING + (t & 511)] = M;
            if (h == 9) {
                out[ 4400 + i * 50 + b] = E;
                out[14400 + i * 50 + b] = I;
                out[24400 + i * 50 + b] = M;
                out[34400 + i * 50 + b] = Evv;
                out[44400 + i * 50 + b] = Ivv;
                out[54400 + i * 50 + b] = Mvv;
            }
        }
        __syncthreads();
    }

    if (c == 0 && i < N_NODE) {
        out[3200 + i * 6 + 0] = M;
        out[3200 + i * 6 + 1] = E;
        out[3200 + i * 6 + 2] = I;
        out[3200 + i * 6 + 3] = Mvv;
        out[3200 + i * 6 + 4] = Evv;
        out[3200 + i * 6 + 5] = Ivv;
    }
    for (int p = tid; p < N_NODE * 500; p += 1024) {
        int ii = p / 500, dd = p - ii * 500;
        out[64400 + p] = ring[ii * RING + (499 - dd)];
    }
    __syncthreads();
    for (int p = tid; p < 64 * 50; p += 1024) {
        int o = p / 50, b = p - o * 50;
        float s = 0.0f;
        for (int n = 0; n < N_NODE; ++n)
            s += lmt[o * N_NODE + n] * (out[4400 + n * 50 + b] - out[14400 + n * 50 + b]);
        out[p] = 5.0f * s - 2.0f;
    }
}

extern "C" void kernel_launch(void* const* d_in, const int* in_sizes, int n_in,
                              void* d_out, int out_size, void* d_ws, size_t ws_size,
                              hipStream_t stream) {
    if (ws_size >= WS_NEED) {
        zero_bar<<<1, 64, 0, stream>>>((int*)((float*)d_ws + OFF_BAR));
        jansen_mw<<<NWG, NTHR, 0, stream>>>(
            (const float*)d_in[0], (const float*)d_in[1], (const float*)d_in[2],
            (const float*)d_in[3], (const float*)d_in[4], (const float*)d_in[5],
            (const float*)d_in[6], (const int*)d_in[7],
            (float*)d_out, (float*)d_ws);
    } else {
        jansen_main<<<1, 1024, 0, stream>>>(
            (const float*)d_in[0], (const float*)d_in[1], (const float*)d_in[2],
            (const float*)d_in[3], (const float*)d_in[4], (const float*)d_in[5],
            (const float*)d_in[6], (const int*)d_in[7],
            (float*)d_out, (float*)d_ws);
    }
}